// Round 7
// baseline (2301.590 us; speedup 1.0000x reference)
//
#include <hip/hip_runtime.h>

typedef unsigned short u16;
typedef __attribute__((ext_vector_type(8))) short short8v;    // MFMA A/B frag (8 bf16)
typedef __attribute__((ext_vector_type(8))) unsigned short ushort8v;
typedef __attribute__((ext_vector_type(4))) unsigned short ushort4v;
typedef __attribute__((ext_vector_type(4))) float f32x4;
typedef __attribute__((ext_vector_type(2))) float f32x2;

__device__ __forceinline__ float bf2f(u16 u) {
    union { unsigned int i; float f; } v; v.i = ((unsigned int)u) << 16; return v.f;
}
__device__ __forceinline__ u16 f2bf(float f) {
    union { float f; unsigned int i; } v; v.f = f;
    unsigned int i = v.i;
    return (u16)((i + 0x7FFFu + ((i >> 16) & 1u)) >> 16);
}
__device__ __forceinline__ float leaky02(float x) { return x > 0.f ? x : 0.2f * x; }
// flag=1: input buffers are packed bf16; flag=0: fp32
__device__ __forceinline__ float load_in(const void* p, long i, int isbf) {
    return isbf ? bf2f(((const u16*)p)[i]) : ((const float*)p)[i];
}
// packed 2xf32 ops (dual-issue FP32 pipe)
__device__ __forceinline__ f32x2 pk_fma(f32x2 a, f32x2 b, f32x2 c) {
    f32x2 d;
    asm("v_pk_fma_f32 %0, %1, %2, %3" : "=v"(d) : "v"(a), "v"(b), "v"(c));
    return d;
}
__device__ __forceinline__ f32x2 pk_add(f32x2 a, f32x2 b) {
    f32x2 d;
    asm("v_pk_add_f32 %0, %1, %2" : "=v"(d) : "v"(a), "v"(b));
    return d;
}
// dword of 2 bf16 -> f32x2 {lo, hi}
__device__ __forceinline__ f32x2 bfpair(unsigned int d) {
    union { unsigned int i; float f; } lo, hi;
    lo.i = d << 16;
    hi.i = d & 0xFFFF0000u;
    f32x2 r; r.x = lo.f; r.y = hi.f; return r;
}
__device__ __forceinline__ float bperm_f(int addr, float v) {
    return __int_as_float(__builtin_amdgcn_ds_bpermute(addr, __float_as_int(v)));
}
__device__ __forceinline__ int bperm_i(int addr, int v) {
    return __builtin_amdgcn_ds_bpermute(addr, v);
}
// async global->LDS DMA, 16B per lane (dest must be wave-uniform-base + lane*16)
#define GLD_LDS16(g, s) __builtin_amdgcn_global_load_lds( \
    (const __attribute__((address_space(1))) void*)(g),   \
    (__attribute__((address_space(3))) void*)(s), 16, 0, 0)

// ---------------------------------------------------------------- dtype detect
__global__ void detect_kernel(const unsigned* __restrict__ w, int* __restrict__ flag) {
    __shared__ int cnt;
    int t = threadIdx.x;
    if (t == 0) cnt = 0;
    __syncthreads();
    unsigned x = w[t * 16];
    unsigned lo = x & 0xFFFFu;
    int e = (int)((x >> 7) & 0xFFu);
    int good = (lo == 0u) || (e >= 100 && e <= 140);
    atomicAdd(&cnt, good);
    __syncthreads();
    if (t == 0) *flag = (cnt > 128) ? 1 : 0;
}

// ---------------------------------------------------------------- CSR build (bucketed)
#define CSR_NBK 1024

__global__ __launch_bounds__(256)
void bucket_count_kernel(const int* __restrict__ ei, int* __restrict__ bcs,
                         int* __restrict__ bcd, int E_, int n, int SH) {
    __shared__ int hs[CSR_NBK], hd[CSR_NBK];
    const int t = threadIdx.x;
    for (int i = t; i < CSR_NBK; i += 256) { hs[i] = 0; hd[i] = 0; }
    __syncthreads();
    const int e0 = blockIdx.x * 4096;
    #pragma unroll
    for (int k = 0; k < 16; ++k) {
        int e = e0 + k * 256 + t;
        if (e < E_) {
            int s = ei[e], d = ei[E_ + e];
            if ((unsigned)s >= (unsigned)n) s = 0;
            if ((unsigned)d >= (unsigned)n) d = 0;
            atomicAdd(&hs[s >> SH], 1);
            atomicAdd(&hd[d >> SH], 1);
        }
    }
    __syncthreads();
    for (int i = t; i < CSR_NBK; i += 256) {
        if (hs[i]) atomicAdd(&bcs[i], hs[i]);
        if (hd[i]) atomicAdd(&bcd[i], hd[i]);
    }
}

__global__ void scan_excl_kernel(const int* __restrict__ deg, int* __restrict__ ptr, int n) {
    __shared__ int s_woff[17];
    __shared__ int s_carry;
    const int t = threadIdx.x;          // 1024 threads
    const int lane = t & 63, wid = t >> 6;
    if (t == 0) s_carry = 0;
    __syncthreads();
    for (int base = 0; base < n; base += 1024) {
        int i = base + t;
        int v = (i < n) ? deg[i] : 0;
        int incl = v;
        #pragma unroll
        for (int d = 1; d < 64; d <<= 1) {
            int x = __shfl_up(incl, d, 64);
            if (lane >= d) incl += x;
        }
        if (lane == 63) s_woff[wid] = incl;
        __syncthreads();
        if (t == 0) {
            int run = 0;
            #pragma unroll
            for (int w = 0; w < 16; ++w) { int x = s_woff[w]; s_woff[w] = run; run += x; }
            s_woff[16] = run;
        }
        __syncthreads();
        int excl = s_carry + s_woff[wid] + incl - v;
        if (i < n) ptr[i] = excl;
        __syncthreads();
        if (t == 0) s_carry += s_woff[16];
        __syncthreads();
    }
    if (t == 0) ptr[n] = s_carry;
}

__global__ void copy2_kernel(const int* __restrict__ a, int* __restrict__ b,
                             const int* __restrict__ c, int* __restrict__ d2, int n) {
    int i = blockIdx.x * 256 + threadIdx.x;
    if (i < n) { b[i] = a[i]; d2[i] = c[i]; }
}

__global__ __launch_bounds__(256)
void partition_kernel(const int* __restrict__ ei, int* __restrict__ bcur_s,
                      int* __restrict__ bcur_d, int2* __restrict__ ps,
                      int2* __restrict__ pd, int E_, int n, int SH) {
    __shared__ int cs[CSR_NBK], cd[CSR_NBK], bs[CSR_NBK], bd[CSR_NBK];
    const int t = threadIdx.x;
    for (int i = t; i < CSR_NBK; i += 256) { cs[i] = 0; cd[i] = 0; }
    __syncthreads();
    const int e0 = blockIdx.x * 4096;
    int sv[16], dv[16];
    #pragma unroll
    for (int k = 0; k < 16; ++k) {
        int e = e0 + k * 256 + t;
        int s = -1, d = 0;
        if (e < E_) {
            s = ei[e]; d = ei[E_ + e];
            if ((unsigned)s >= (unsigned)n) s = 0;
            if ((unsigned)d >= (unsigned)n) d = 0;
            atomicAdd(&cs[s >> SH], 1);
            atomicAdd(&cd[d >> SH], 1);
        }
        sv[k] = (e < E_) ? s : -1;
        dv[k] = d;
    }
    __syncthreads();
    for (int i = t; i < CSR_NBK; i += 256) {
        bs[i] = cs[i] ? atomicAdd(&bcur_s[i], cs[i]) : 0;
        bd[i] = cd[i] ? atomicAdd(&bcur_d[i], cd[i]) : 0;
        cs[i] = 0; cd[i] = 0;
    }
    __syncthreads();
    #pragma unroll
    for (int k = 0; k < 16; ++k) {
        int s = sv[k];
        if (s < 0) continue;
        int d = dv[k];
        int p = bs[s >> SH] + atomicAdd(&cs[s >> SH], 1);
        ps[p] = make_int2(d, s);          // (payload, key)
        int q = bd[d >> SH] + atomicAdd(&cd[d >> SH], 1);
        pd[q] = make_int2(s, d);
    }
}

__global__ __launch_bounds__(256)
void fill_bucket_kernel(const int2* __restrict__ pairs, const int* __restrict__ bptr,
                        int* __restrict__ ptr, int* __restrict__ idx, int n, int SH) {
    __shared__ int cnt[256];
    __shared__ int wsum[5];
    const int b = blockIdx.x;
    const int n0 = b << SH;
    if (n0 >= n) return;
    const int nn = min(1 << SH, n - n0);
    const int t = threadIdx.x;
    cnt[t] = 0;
    __syncthreads();
    const int pbeg = bptr[b], pend = bptr[b + 1];
    for (int j = pbeg + t; j < pend; j += 256)
        atomicAdd(&cnt[pairs[j].y - n0], 1);
    __syncthreads();
    const int c = (t < nn) ? cnt[t] : 0;
    int v = c;
    const int lane = t & 63, wid = t >> 6;
    #pragma unroll
    for (int d = 1; d < 64; d <<= 1) {
        int x = __shfl_up(v, d, 64);
        if (lane >= d) v += x;
    }
    if (lane == 63) wsum[wid] = v;
    __syncthreads();
    if (t == 0) {
        int r = 0;
        #pragma unroll
        for (int w = 0; w < 4; ++w) { int x = wsum[w]; wsum[w] = r; r += x; }
        wsum[4] = r;
    }
    __syncthreads();
    v += wsum[wid];
    const int excl = pbeg + v - c;        // exclusive offset for node n0+t
    __syncthreads();                       // all reads of cnt done; safe to overwrite
    if (t < nn) { cnt[t] = excl; ptr[n0 + t] = excl; }
    if (t == 0 && n0 + nn == n) ptr[n] = pbeg + wsum[4];   // == pend
    __syncthreads();
    for (int j = pbeg + t; j < pend; j += 256) {
        int2 pr = pairs[j];
        int p = atomicAdd(&cnt[pr.y - n0], 1);
        idx[p] = pr.x;
    }
}

// ---------------------------------------------------------------- ingest (dtype-aware)
__global__ void ingest_transpose_kernel(const void* __restrict__ src, long base,
                                        u16* __restrict__ dst, int K, int Nc, int Kp,
                                        const int* __restrict__ flag) {
    int i = blockIdx.x * 256 + threadIdx.x;
    if (i >= Nc * Kp) return;
    int n = i / Kp, k = i - n * Kp;
    float v = (k < K) ? load_in(src, base + (long)k * Nc + n, *flag) : 0.f;
    dst[i] = f2bf(v);
}

// 8 small bias/vector copies batched into one launch (blocks 0-5: 256, 6-7: 128)
__global__ void ingest_vecs_kernel(const void* __restrict__ s0, const void* __restrict__ s1,
                                   const void* __restrict__ s2, const void* __restrict__ s3,
                                   const void* __restrict__ s4, const void* __restrict__ s5,
                                   const void* __restrict__ s6, const void* __restrict__ s7,
                                   u16* __restrict__ d0, u16* __restrict__ d1,
                                   u16* __restrict__ d2, u16* __restrict__ d3,
                                   u16* __restrict__ d4, u16* __restrict__ d5,
                                   u16* __restrict__ d6, u16* __restrict__ d7,
                                   const int* __restrict__ flag) {
    const void* srcs[8] = {s0, s1, s2, s3, s4, s5, s6, s7};
    u16* dsts[8] = {d0, d1, d2, d3, d4, d5, d6, d7};
    const int b = blockIdx.x, t = threadIdx.x;
    const int nsz = (b < 6) ? 256 : 128;
    if (t < nsz) dsts[b][t] = f2bf(load_in(srcs[b], t, *flag));
}

__global__ void ingest_wcat_kernel(const void* __restrict__ W, u16* __restrict__ dst,
                                   int Kin, int Fh, const int* __restrict__ flag) {
    int i = blockIdx.x * 256 + threadIdx.x;
    int tot = 256 * 2 * Fh;
    if (i >= tot) return;
    int o = i / (2 * Fh), k = i - o * 2 * Fh;
    int h = k / Fh, c = k - h * Fh;
    float v = (c < Kin) ? 0.5f * load_in(W, (long)c * 512 + h * 256 + o, *flag) : 0.f;
    dst[i] = f2bf(v);
}

__global__ void ingest_bcat_kernel(const void* __restrict__ fc1, const void* __restrict__ fc2,
                                   u16* __restrict__ dst, const int* __restrict__ flag) {
    int i = blockIdx.x * 256 + threadIdx.x;
    if (i >= 256 * 512) return;
    int o = i >> 9, k = i & 511;
    float v = (k < 256) ? load_in(fc1, (long)o * 256 + k, *flag)
                        : load_in(fc2, (long)o * 256 + k - 256, *flag);
    dst[i] = f2bf(v);
}

__global__ void ingest_pad_molx_kernel(const void* __restrict__ x, u16* __restrict__ dst,
                                       int ldd, int total, const int* __restrict__ flag) {
    int i = blockIdx.x * 256 + threadIdx.x;
    if (i >= total) return;
    int r = i / 96, c = i - r * 96;
    float v = (c < 78) ? load_in(x, (long)r * 78 + c, *flag) : 0.f;
    dst[(size_t)r * ldd + c] = f2bf(v);
}

__global__ void attn_vec_kernel(const void* __restrict__ W, const void* __restrict__ as_,
                                const void* __restrict__ ad_, float* __restrict__ was,
                                float* __restrict__ wad, int Kin, int Fh,
                                const int* __restrict__ flag) {
    int i = blockIdx.x * 256 + threadIdx.x;
    if (i >= 2 * Fh) return;
    int h = i / Fh, c = i - h * Fh;
    float s = 0.f, d = 0.f;
    if (c < Kin) {
        int f = *flag;
        for (int o = 0; o < 256; ++o) {
            float w = load_in(W, (long)c * 512 + h * 256 + o, f);
            s += w * load_in(as_, h * 256 + o, f);
            d += w * load_in(ad_, h * 256 + o, f);
        }
    }
    was[i] = s; wad[i] = d;
}

// ---------------------------------------------------------------- GEMM (bf16 MFMA)
// Staging via global_load_lds width-16 DMA. LDS dest = wave*1024 + lane*16 (legal DMA).
__global__ __launch_bounds__(256, 2)
void gemm_kernel(const u16* __restrict__ A, int lda,
                 const u16* __restrict__ Bt, int ldb,
                 u16* __restrict__ C, int ldc, int K, int M, int beta,
                 const u16* __restrict__ bias, int relu) {
    __shared__ __align__(16) u16 As[128 * 32];
    __shared__ __align__(16) u16 Bs[128 * 32];
    const int tid = threadIdx.x;
    const int wave = tid >> 6, lane = tid & 63;
    const int m0 = blockIdx.x * 128;
    const int n0 = blockIdx.y * 128;
    const int wm = (wave & 1) * 64, wn = (wave >> 1) * 64;
    const int r = lane & 15, q = lane >> 4;

    f32x4 acc[4][4];
    if (beta) {
        #pragma unroll
        for (int i = 0; i < 4; ++i)
            #pragma unroll
            for (int j = 0; j < 4; ++j)
                #pragma unroll
                for (int rr = 0; rr < 4; ++rr) {
                    size_t gr = (size_t)(m0 + wm + 16 * i + q * 4 + rr);
                    int gc = n0 + wn + 16 * j + r;
                    acc[i][j][rr] = bf2f(C[gr * ldc + gc]);
                }
    } else {
        #pragma unroll
        for (int i = 0; i < 4; ++i)
            #pragma unroll
            for (int j = 0; j < 4; ++j) acc[i][j] = (f32x4)0.f;
    }

    const int rowT = wave * 16 + (lane >> 2);
    const int koff = (lane & 3) * 8;
    int rA0 = m0 + rowT;       if (rA0 > M - 1) rA0 = M - 1;
    int rA1 = m0 + rowT + 64;  if (rA1 > M - 1) rA1 = M - 1;
    const u16* gA0 = A + (size_t)rA0 * lda + koff;
    const u16* gA1 = A + (size_t)rA1 * lda + koff;
    const u16* gB0 = Bt + (size_t)(n0 + rowT) * ldb + koff;
    const u16* gB1 = Bt + (size_t)(n0 + rowT + 64) * ldb + koff;
    u16* sA0 = &As[rowT * 32 + koff];
    u16* sA1 = &As[(rowT + 64) * 32 + koff];
    u16* sB0 = &Bs[rowT * 32 + koff];
    u16* sB1 = &Bs[(rowT + 64) * 32 + koff];

    const int nK = K >> 5;
    for (int kt = 0; kt < nK; ++kt) {
        __syncthreads();
        GLD_LDS16(gA0, sA0);
        GLD_LDS16(gA1, sA1);
        GLD_LDS16(gB0, sB0);
        GLD_LDS16(gB1, sB1);
        gA0 += 32; gA1 += 32; gB0 += 32; gB1 += 32;
        __syncthreads();
        short8v af[4], bf[4];
        #pragma unroll
        for (int i = 0; i < 4; ++i) af[i] = *(const short8v*)&As[(wm + 16 * i + r) * 32 + q * 8];
        #pragma unroll
        for (int j = 0; j < 4; ++j) bf[j] = *(const short8v*)&Bs[(wn + 16 * j + r) * 32 + q * 8];
        #pragma unroll
        for (int i = 0; i < 4; ++i)
            #pragma unroll
            for (int j = 0; j < 4; ++j)
                acc[i][j] = __builtin_amdgcn_mfma_f32_16x16x32_bf16(af[i], bf[j], acc[i][j], 0, 0, 0);
    }
    // C/D layout: col = lane&15, row = (lane>>4)*4 + reg
    #pragma unroll
    for (int j = 0; j < 4; ++j) {
        int gc = n0 + wn + 16 * j + r;
        float bv = bias ? bf2f(bias[gc]) : 0.f;
        #pragma unroll
        for (int i = 0; i < 4; ++i)
            #pragma unroll
            for (int rr = 0; rr < 4; ++rr) {
                size_t gr = (size_t)(m0 + wm + 16 * i + q * 4 + rr);
                float x = acc[i][j][rr] + bv;
                if (relu) x = fmaxf(x, 0.f);
                C[gr * ldc + gc] = f2bf(x);
            }
    }
}

// ---------------------------------------------------------------- GEMM + gate (fused)
// logits = cat @ Bcat^T (128x256 tile/block, grid 1-D over M -> each block OWNS its
// 128 rows exclusively, so the in-place cat.h overwrite is race-free). Epilogue:
// z = sigmoid(logit + b); h_new = z*x + (1-z)*h written to cat.h (+ optional d_out).
// Eliminates the 51MB logits write + 51MB read-back + the gate kernel.
__global__ __launch_bounds__(256)
void gemm_gate_kernel(u16* __restrict__ A /*cat, ld=lda, written in-place*/, int lda,
                      const u16* __restrict__ Bt, int ldb, int K,
                      const u16* __restrict__ fc1b, const u16* __restrict__ fc2b,
                      const u16* __restrict__ molb, void* __restrict__ outw,
                      const int* __restrict__ flag, int n) {
    __shared__ __align__(16) u16 As[128 * 32];
    __shared__ __align__(16) u16 Bs[256 * 32];
    const int tid = threadIdx.x;
    const int wave = tid >> 6, lane = tid & 63;
    const int m0 = blockIdx.x * 128;
    const int wm = (wave & 1) * 64, wn = (wave >> 1) * 128;
    const int r = lane & 15, q = lane >> 4;

    f32x4 acc[4][8];
    #pragma unroll
    for (int i = 0; i < 4; ++i)
        #pragma unroll
        for (int j = 0; j < 8; ++j) acc[i][j] = (f32x4)0.f;

    const int koff = (tid & 3) * 8;
    const u16* gA0 = A + (size_t)(m0 + (tid >> 2)) * lda + koff;
    const u16* gA1 = A + (size_t)(m0 + (tid >> 2) + 64) * lda + koff;
    const u16* gB0 = Bt + (size_t)(tid >> 2) * ldb + koff;
    const u16* gB1 = Bt + (size_t)((tid >> 2) + 64) * ldb + koff;
    const u16* gB2 = Bt + (size_t)((tid >> 2) + 128) * ldb + koff;
    const u16* gB3 = Bt + (size_t)((tid >> 2) + 192) * ldb + koff;
    u16* sA0 = &As[tid * 8];
    u16* sA1 = &As[(tid + 256) * 8];
    u16* sB0 = &Bs[tid * 8];
    u16* sB1 = &Bs[(tid + 256) * 8];
    u16* sB2 = &Bs[(tid + 512) * 8];
    u16* sB3 = &Bs[(tid + 768) * 8];

    const int nK = K >> 5;
    for (int kt = 0; kt < nK; ++kt) {
        __syncthreads();
        GLD_LDS16(gA0, sA0);
        GLD_LDS16(gA1, sA1);
        GLD_LDS16(gB0, sB0);
        GLD_LDS16(gB1, sB1);
        GLD_LDS16(gB2, sB2);
        GLD_LDS16(gB3, sB3);
        gA0 += 32; gA1 += 32; gB0 += 32; gB1 += 32; gB2 += 32; gB3 += 32;
        __syncthreads();
        short8v af[4], bf[8];
        #pragma unroll
        for (int i = 0; i < 4; ++i) af[i] = *(const short8v*)&As[(wm + 16 * i + r) * 32 + q * 8];
        #pragma unroll
        for (int j = 0; j < 8; ++j) bf[j] = *(const short8v*)&Bs[(wn + 16 * j + r) * 32 + q * 8];
        #pragma unroll
        for (int i = 0; i < 4; ++i)
            #pragma unroll
            for (int j = 0; j < 8; ++j)
                acc[i][j] = __builtin_amdgcn_mfma_f32_16x16x32_bf16(af[i], bf[j], acc[i][j], 0, 0, 0);
    }
    const int fl = *flag;
    #pragma unroll
    for (int j = 0; j < 8; ++j) {
        const int gc = wn + 16 * j + r;                 // 0..255
        const float bsum = bf2f(fc1b[gc]) + bf2f(fc2b[gc]) + bf2f(molb[gc]);
        #pragma unroll
        for (int i = 0; i < 4; ++i)
            #pragma unroll
            for (int rr = 0; rr < 4; ++rr) {
                const int gr = m0 + wm + 16 * i + q * 4 + rr;
                const size_t rb = (size_t)gr * lda;
                const float l = acc[i][j][rr] + bsum;
                const float z = 1.f / (1.f + __expf(-l));
                const float x = bf2f(A[rb + gc]);
                const float h = bf2f(A[rb + 256 + gc]);
                const float o = z * x + (1.f - z) * h;
                A[rb + 256 + gc] = f2bf(o);             // in-place h update (own rows)
                if (outw && gr < n) {
                    if (fl) ((u16*)outw)[(size_t)gr * 384 + gc] = f2bf(o);
                    else    ((float*)outw)[(size_t)gr * 384 + gc] = o;
                }
            }
    }
}

// ---------------------------------------------------------------- attention dots (h-space)
__global__ __launch_bounds__(256)
void attn_dots_h_kernel(const u16* __restrict__ hsrc, int ldh,
                        const float* __restrict__ was, const float* __restrict__ wad,
                        float* __restrict__ a_src, float* __restrict__ a_dst,
                        int Fh, int n) {
    int v = blockIdx.x * 4 + (threadIdx.x >> 6);
    if (v >= n) return;
    const int lane = threadIdx.x & 63;
    const int c0 = lane * 4;
    float ps0 = 0.f, pd0 = 0.f, ps1 = 0.f, pd1 = 0.f;
    if (c0 < Fh) {
        ushort4v xv = *(const ushort4v*)&hsrc[(size_t)v * ldh + c0];
        #pragma unroll
        for (int k = 0; k < 4; ++k) {
            float x = bf2f(xv[k]);
            ps0 += x * was[c0 + k];
            pd0 += x * wad[c0 + k];
            ps1 += x * was[Fh + c0 + k];
            pd1 += x * wad[Fh + c0 + k];
        }
    }
    #pragma unroll
    for (int d = 1; d < 64; d <<= 1) {
        ps0 += __shfl_xor(ps0, d, 64); pd0 += __shfl_xor(pd0, d, 64);
        ps1 += __shfl_xor(ps1, d, 64); pd1 += __shfl_xor(pd1, d, 64);
    }
    if (lane == 0) {
        a_src[2 * v] = ps0; a_src[2 * v + 1] = ps1;
        a_dst[2 * v] = pd0; a_dst[2 * v + 1] = pd1;
    }
}

// ---------------------------------------------------------------- GAT aggregate
// Round-3 bperm structure (best measured) + no-max softmax (validated round 6:
// scores O(+-2), clamp 80 for inf-safety; exp shift-invariance makes max optional).
// Weight phase: each lane computes ONE edge's w=exp(score) (no duplication, exp once
// per edge). Feature phase: wave-uniform trip count; (src,w) via register bperm.
// Lanes >= cnt stay ACTIVE with w=0 -> bperm sources always valid.
template <int NG>
__global__ __launch_bounds__(256)
void gat_agg_h_kernel(const u16* __restrict__ hsrc, int ldh, int F,
                      const float* __restrict__ asrc, const float* __restrict__ adst,
                      const int* __restrict__ ptr, const int* __restrict__ idx,
                      u16* __restrict__ agg, int ldagg, int n, int Etot) {
    constexpr int GL = 64 / NG;           // lanes per edge group
    int v = blockIdx.x * 4 + (threadIdx.x >> 6);
    if (v >= n) return;
    const int lane = threadIdx.x & 63;
    const int sub = lane / GL;            // edge slot within chunk parity
    const int c0 = (lane & (GL - 1)) * 8; // 8 cols per lane
    const int act = (c0 < F);
    int beg = ptr[v], end = ptr[v + 1];
    beg = min(max(beg, 0), Etot);
    end = min(max(end, beg), Etot);
    const float ad0 = adst[2 * v], ad1 = adst[2 * v + 1];
    const float es0 = fminf(leaky02(asrc[2 * v] + ad0), 80.f);
    const float es1 = fminf(leaky02(asrc[2 * v + 1] + ad1), 80.f);
    float s0 = 0.f, s1 = 0.f;             // per-lane partial exp-sums
    f32x2 f0p[4], f1p[4];
    #pragma unroll
    for (int p = 0; p < 4; ++p) { f0p[p] = (f32x2)0.f; f1p[p] = (f32x2)0.f; }

    for (int cb = beg; cb < end; cb += 64) {
        const int cnt = min(64, end - cb);   // wave-uniform
        // ---- weight phase: one edge per lane; lanes >= cnt hold weight 0
        int sE = 0;
        float wE0 = 0.f, wE1 = 0.f;
        if (lane < cnt) {
            sE = idx[cb + lane];
            sE = ((unsigned)sE < (unsigned)n) ? sE : 0;
            const float2 ap = *(const float2*)&asrc[2 * sE];
            wE0 = __expf(fminf(leaky02(ap.x + ad0), 80.f));
            wE1 = __expf(fminf(leaky02(ap.y + ad1), 80.f));
            s0 += wE0; s1 += wE1;
        }
        // ---- feature phase: NG edges in flight, wave-uniform trip count.
        // max source lane = nIt*2NG - 1 <= 63 (cnt <= 64, 2NG | 64): no clamp needed.
        const int nIt = (cnt + 2 * NG - 1) / (2 * NG);
        int jj = sub;
        for (int it = 0; it < nIt; ++it, jj += 2 * NG) {
            const int aA = jj * 4, aB = aA + NG * 4;
            const int sA = bperm_i(aA, sE);
            const float wA0 = bperm_f(aA, wE0), wA1 = bperm_f(aA, wE1);
            const int sB = bperm_i(aB, sE);
            const float wB0 = bperm_f(aB, wE0), wB1 = bperm_f(aB, wE1);
            if (act) {
                const uint4 fA = *(const uint4*)&hsrc[(size_t)sA * ldh + c0];
                const uint4 fB = *(const uint4*)&hsrc[(size_t)sB * ldh + c0];
                const f32x2 wA0v = {wA0, wA0}, wA1v = {wA1, wA1};
                const f32x2 wB0v = {wB0, wB0}, wB1v = {wB1, wB1};
                #pragma unroll
                for (int p = 0; p < 4; ++p) {
                    const f32x2 xA = bfpair(((const unsigned*)&fA)[p]);
                    const f32x2 xB = bfpair(((const unsigned*)&fB)[p]);
                    f0p[p] = pk_fma(xA, wA0v, f0p[p]);
                    f1p[p] = pk_fma(xA, wA1v, f1p[p]);
                    f0p[p] = pk_fma(xB, wB0v, f0p[p]);
                    f1p[p] = pk_fma(xB, wB1v, f1p[p]);
                }
            }
        }
    }
    // reduce exp-sums across all 64 lanes
    #pragma unroll
    for (int d = 1; d < 64; d <<= 1) {
        s0 += __shfl_xor(s0, d, 64);
        s1 += __shfl_xor(s1, d, 64);
    }
    const float w0s = __expf(es0), w1s = __expf(es1);
    s0 += w0s; s1 += w1s;
    if (sub == 0 && act) {   // self-loop features
        const uint4 f = *(const uint4*)&hsrc[(size_t)v * ldh + c0];
        const f32x2 w0v = {w0s, w0s}, w1v = {w1s, w1s};
        #pragma unroll
        for (int p = 0; p < 4; ++p) {
            const f32x2 x = bfpair(((const unsigned*)&f)[p]);
            f0p[p] = pk_fma(x, w0v, f0p[p]);
            f1p[p] = pk_fma(x, w1v, f1p[p]);
        }
    }
    // reduce feature partials across edge groups
    #pragma unroll
    for (int p = 0; p < 4; ++p) {
        #pragma unroll
        for (int d = GL; d < 64; d <<= 1) {
            f0p[p].x += __shfl_xor(f0p[p].x, d, 64);
            f0p[p].y += __shfl_xor(f0p[p].y, d, 64);
            f1p[p].x += __shfl_xor(f1p[p].x, d, 64);
            f1p[p].y += __shfl_xor(f1p[p].y, d, 64);
        }
    }
    if (lane < GL && act) {
        const float i0 = 1.f / s0, i1 = 1.f / s1;
        ushort8v o0, o1;
        #pragma unroll
        for (int p = 0; p < 4; ++p) {
            o0[2 * p] = f2bf(f0p[p].x * i0); o0[2 * p + 1] = f2bf(f0p[p].y * i0);
            o1[2 * p] = f2bf(f1p[p].x * i1); o1[2 * p + 1] = f2bf(f1p[p].y * i1);
        }
        *(ushort8v*)&agg[(size_t)v * ldagg + c0] = o0;
        *(ushort8v*)&agg[(size_t)v * ldagg + F + c0] = o1;
    }
}

// ---------------------------------------------------------------- hypergraph gather
// res[v] = inv_deg * sum feat[idx[j]] (+bias, relu); F=128 fixed. 4 sub-groups x
// 4 rows in flight (16 concurrent gathers/wave), pk add.
__global__ __launch_bounds__(256)
void hyper_gather_kernel(const u16* __restrict__ feat, const int* __restrict__ ptr,
                         const int* __restrict__ idx, const u16* __restrict__ bias,
                         u16* __restrict__ outb, int ldo, void* __restrict__ outw,
                         int col0, const int* __restrict__ flag,
                         int do_relu, int n, int Etot) {
    int v = blockIdx.x * 4 + (threadIdx.x >> 6);
    if (v >= n) return;
    const int lane = threadIdx.x & 63;
    const int c0 = (lane & 15) * 8, sub = lane >> 4;
    int beg = ptr[v], end = ptr[v + 1];
    beg = min(max(beg, 0), Etot);
    end = min(max(end, beg), Etot);
    const float inv = (end > beg) ? 1.f / (float)(end - beg) : 0.f;
    f32x2 a2[4];
    #pragma unroll
    for (int p = 0; p < 4; ++p) a2[p] = (f32x2)0.f;
    int j = beg + sub;
    for (; j + 12 < end; j += 16) {
        int sA = idx[j];      sA = ((unsigned)sA < (unsigned)n) ? sA : 0;
        int sB = idx[j + 4];  sB = ((unsigned)sB < (unsigned)n) ? sB : 0;
        int sC = idx[j + 8];  sC = ((unsigned)sC < (unsigned)n) ? sC : 0;
        int sD = idx[j + 12]; sD = ((unsigned)sD < (unsigned)n) ? sD : 0;
        const uint4 fA = *(const uint4*)&feat[(size_t)sA * 128 + c0];
        const uint4 fB = *(const uint4*)&feat[(size_t)sB * 128 + c0];
        const uint4 fC = *(const uint4*)&feat[(size_t)sC * 128 + c0];
        const uint4 fD = *(const uint4*)&feat[(size_t)sD * 128 + c0];
        #pragma unroll
        for (int p = 0; p < 4; ++p) {
            a2[p] = pk_add(a2[p], bfpair(((const unsigned*)&fA)[p]));
            a2[p] = pk_add(a2[p], bfpair(((const unsigned*)&fB)[p]));
            a2[p] = pk_add(a2[p], bfpair(((const unsigned*)&fC)[p]));
            a2[p] = pk_add(a2[p], bfpair(((const unsigned*)&fD)[p]));
        }
    }
    for (; j < end; j += 4) {
        int s = idx[j]; s = ((unsigned)s < (unsigned)n) ? s : 0;
        const uint4 f = *(const uint4*)&feat[(size_t)s * 128 + c0];
        #pragma unroll
        for (int p = 0; p < 4; ++p)
            a2[p] = pk_add(a2[p], bfpair(((const unsigned*)&f)[p]));
    }
    #pragma unroll
    for (int p = 0; p < 4; ++p) {
        a2[p].x += __shfl_xor(a2[p].x, 16, 64);
        a2[p].y += __shfl_xor(a2[p].y, 16, 64);
        a2[p].x += __shfl_xor(a2[p].x, 32, 64);
        a2[p].y += __shfl_xor(a2[p].y, 32, 64);
    }
    if (sub == 0) {
        float ov[8];
        ushort8v o;
        #pragma unroll
        for (int p = 0; p < 4; ++p) {
            float x0 = a2[p].x * inv + (bias ? bf2f(bias[c0 + 2 * p]) : 0.f);
            float x1 = a2[p].y * inv + (bias ? bf2f(bias[c0 + 2 * p + 1]) : 0.f);
            if (do_relu) { x0 = fmaxf(x0, 0.f); x1 = fmaxf(x1, 0.f); }
            ov[2 * p] = x0; ov[2 * p + 1] = x1;
            o[2 * p] = f2bf(x0); o[2 * p + 1] = f2bf(x1);
        }
        if (outb) *(ushort8v*)&outb[(size_t)v * ldo + c0] = o;
        if (outw) {
            if (*flag) {
                *(ushort8v*)((u16*)outw + (size_t)v * 384 + col0 + c0) = o;
            } else {
                float* ofp = (float*)outw + (size_t)v * 384 + col0 + c0;
                #pragma unroll
                for (int k = 0; k < 8; ++k) ofp[k] = ov[k];
            }
        }
    }
}

// ================================================================ launch
extern "C" void kernel_launch(void* const* d_in, const int* in_sizes, int n_in,
                              void* d_out, int out_size, void* d_ws, size_t ws_size,
                              hipStream_t stream) {
    const void* molx = d_in[0];
    const int*  ei   = (const int*)d_in[1];
    const void* W1 = d_in[3], *as1 = d_in[4], *ad1 = d_in[5], *b1 = d_in[6];
    const void* W2 = d_in[7], *as2 = d_in[8], *ad2 = d_in[9], *b2 = d_in[10];
    const void* W3 = d_in[11], *as3 = d_in[12], *ad3 = d_in[13], *b3 = d_in[14];
    const void* fc1w = d_in[15], *fc1b = d_in[16], *fc2w = d_in[17], *fc2b = d_in[18];
    const void* molb = d_in[19];
    const void* th1 = d_in[20], *hb1 = d_in[21], *th2 = d_in[22], *hb2 = d_in[23];
    (void)n_in; (void)out_size;

    const int N = in_sizes[0] / 78;
    const int E = in_sizes[1] / 2;
    const int Mp = ((N + 127) / 128) * 128;

    // bucket shift: at most 1024 buckets, bucket width <= 256 nodes (N <= 262144)
    int SH = 0;
    while (((N - 1) >> SH) >= CSR_NBK) SH++;

    // ---- workspace
    char* base = (char*)d_ws;
    size_t off = 0;
    auto alloc = [&](size_t bytes) -> void* {
        void* r = base + off;
        off = (off + bytes + 255) & ~(size_t)255;
        return r;
    };
    int* flag = (int*)alloc(4);
    u16* bv1 = (u16*)alloc(256 * 2); u16* bv2 = (u16*)alloc(256 * 2); u16* bv3 = (u16*)alloc(256 * 2);
    u16* fc1bv = (u16*)alloc(256 * 2); u16* fc2bv = (u16*)alloc(256 * 2); u16* molbv = (u16*)alloc(256 * 2);
    u16* hb1v = (u16*)alloc(128 * 2); u16* hb2v = (u16*)alloc(128 * 2);
    float* was1 = (float*)alloc(192 * 4); float* wad1 = (float*)alloc(192 * 4);
    float* was2 = (float*)alloc(512 * 4); float* wad2 = (float*)alloc(512 * 4);
    float* was3 = (float*)alloc(512 * 4); float* wad3 = (float*)alloc(512 * 4);
    u16* Wc1 = (u16*)alloc(256 * 192 * 2);
    u16* Wc2 = (u16*)alloc(256 * 512 * 2);
    u16* Wc3 = (u16*)alloc(256 * 512 * 2);
    u16* Bcat = (u16*)alloc(256 * 512 * 2);
    u16* th1ta = (u16*)alloc(128 * 256 * 2);
    u16* th1tb = (u16*)alloc(128 * 96 * 2);
    u16* th2t  = (u16*)alloc(128 * 128 * 2);
    float* a_src = (float*)alloc((size_t)N * 2 * 4);
    float* a_dst = (float*)alloc((size_t)N * 2 * 4);
    int* ptr_src = (int*)alloc((size_t)(N + 1) * 4);
    int* ptr_dst = (int*)alloc((size_t)(N + 1) * 4);
    int* bcnt_src = (int*)alloc(CSR_NBK * 4);
    int* bcnt_dst = (int*)alloc(CSR_NBK * 4);
    int* bptr_src = (int*)alloc((CSR_NBK + 1) * 4);
    int* bptr_dst = (int*)alloc((CSR_NBK + 1) * 4);
    int* bcur_src = (int*)alloc(CSR_NBK * 4);
    int* bcur_dst = (int*)alloc(CSR_NBK * 4);
    int* idx_src = (int*)alloc((size_t)E * 4);
    int* idx_dst = (int*)alloc((size_t)E * 4);
    u16* cat = (u16*)alloc((size_t)Mp * 512 * 2);   // [x | h] per row (ld 512)
    u16* agg = (u16*)alloc((size_t)Mp * 512 * 2);   // agg / hyper regions
    // hyper-phase regions inside agg:
    u16* xt   = agg;                         // Mp x 128
    u16* efb  = agg + (size_t)Mp * 128;      // N x 128
    u16* hx1  = agg + (size_t)Mp * 256;      // N x 128
    u16* mxp2 = agg + (size_t)Mp * 384;      // Mp x 96 (re-ingested mol_x for hyper GEMM)

    // pair buffers (bucket-major (payload,key)): dedicated if ws allows, else borrow agg
    int2* pairs_src; int2* pairs_dst;
    if (off + (size_t)E * 16 + 1024 <= ws_size) {
        pairs_src = (int2*)alloc((size_t)E * 8);
        pairs_dst = (int2*)alloc((size_t)E * 8);
    } else {
        pairs_src = (int2*)agg;
        pairs_dst = (int2*)((char*)agg + (size_t)E * 8);
    }

    const int nodeBlocks = (N + 3) / 4;
    const int eTiles = (E + 4095) / 4096;

    // ---- dtype detect (precedes all ingest)
    detect_kernel<<<1, 256, 0, stream>>>((const unsigned*)molx, flag);

    // ---- CSR build (bucketed two-level scatter)
    hipMemsetAsync(bcnt_src, 0, CSR_NBK * 4, stream);
    hipMemsetAsync(bcnt_dst, 0, CSR_NBK * 4, stream);
    bucket_count_kernel<<<eTiles, 256, 0, stream>>>(ei, bcnt_src, bcnt_dst, E, N, SH);
    scan_excl_kernel<<<1, 1024, 0, stream>>>(bcnt_src, bptr_src, CSR_NBK);
    scan_excl_kernel<<<1, 1024, 0, stream>>>(bcnt_dst, bptr_dst, CSR_NBK);
    copy2_kernel<<<(CSR_NBK + 255) / 256, 256, 0, stream>>>(bptr_src, bcur_src, bptr_dst, bcur_dst, CSR_NBK);
    partition_kernel<<<eTiles, 256, 0, stream>>>(ei, bcur_src, bcur_dst,
                                                 pairs_src, pairs_dst, E, N, SH);
    fill_bucket_kernel<<<CSR_NBK, 256, 0, stream>>>(pairs_src, bptr_src, ptr_src, idx_src, N, SH);
    fill_bucket_kernel<<<CSR_NBK, 256, 0, stream>>>(pairs_dst, bptr_dst, ptr_dst, idx_dst, N, SH);

    // ---- weight/vector ingest
    ingest_wcat_kernel<<<(256 * 192 + 255) / 256, 256, 0, stream>>>(W1, Wc1, 78, 96, flag);
    ingest_wcat_kernel<<<(256 * 512 + 255) / 256, 256, 0, stream>>>(W2, Wc2, 256, 256, flag);
    ingest_wcat_kernel<<<(256 * 512 + 255) / 256, 256, 0, stream>>>(W3, Wc3, 256, 256, flag);
    ingest_bcat_kernel<<<(256 * 512 + 255) / 256, 256, 0, stream>>>(fc1w, fc2w, Bcat, flag);
    ingest_transpose_kernel<<<(128 * 256 + 255) / 256, 256, 0, stream>>>(th1, 0, th1ta, 256, 128, 256, flag);
    ingest_transpose_kernel<<<(128 * 96 + 255) / 256, 256, 0, stream>>>(th1, (long)256 * 128, th1tb, 78, 128, 96, flag);
    ingest_transpose_kernel<<<(128 * 128 + 255) / 256, 256, 0, stream>>>(th2, 0, th2t, 128, 128, 128, flag);
    attn_vec_kernel<<<1, 256, 0, stream>>>(W1, as1, ad1, was1, wad1, 78, 96, flag);
    attn_vec_kernel<<<2, 256, 0, stream>>>(W2, as2, ad2, was2, wad2, 256, 256, flag);
    attn_vec_kernel<<<2, 256, 0, stream>>>(W3, as3, ad3, was3, wad3, 256, 256, flag);
    ingest_vecs_kernel<<<8, 256, 0, stream>>>(b1, b2, b3, fc1b, fc2b, molb, hb1, hb2,
                                              bv1, bv2, bv3, fc1bv, fc2bv, molbv,
                                              hb1v, hb2v, flag);
    // mol_x padded into cat cols [0,96) (x-region unused until layer 2)
    ingest_pad_molx_kernel<<<(N * 96 + 255) / 256, 256, 0, stream>>>(molx, cat, 512, N * 96, flag);

    auto gemm = [&](const u16* A, int lda, const u16* Bt, int ldb, u16* C, int ldc,
                    int K, int Nc, int M, int beta, const u16* bias, int relu) {
        dim3 g(Mp / 128, Nc / 128);
        gemm_kernel<<<g, 256, 0, stream>>>(A, lda, Bt, ldb, C, ldc, K, M, beta, bias, relu);
    };

    // ---- GAT layer 1: agg over mol_x (F=96) -> h1 = relu(agg@Wc1 + b1) -> cat.h
    attn_dots_h_kernel<<<nodeBlocks, 256, 0, stream>>>(cat, 512, was1, wad1, a_src, a_dst, 96, N);
    gat_agg_h_kernel<4><<<nodeBlocks, 256, 0, stream>>>(cat, 512, 96, a_src, a_dst,
                                                        ptr_dst, idx_dst, agg, 192, N, E);
    gemm(agg, 192, Wc1, 192, cat + 256, 512, 192, 256, Mp, 0, bv1, 1);
    // ---- GAT layer 2: agg over h1 -> x2 = relu(agg@Wc2 + b2) -> cat.x; fused gate -> cat.h
    attn_dots_h_kernel<<<nodeBlocks, 256, 0, stream>>>(cat + 256, 512, was2, wad2, a_src, a_dst, 256, N);
    gat_agg_h_kernel<2><<<nodeBlocks, 256, 0, stream>>>(cat + 256, 512, 256, a_src, a_dst,
                                                        ptr_dst, idx_dst, agg, 512, N, E);
    gemm(agg, 512, Wc2, 512, cat, 512, 512, 256, Mp, 0, bv2, 1);
    gemm_gate_kernel<<<Mp / 128, 256, 0, stream>>>(cat, 512, Bcat, 512, 512,
                                                   fc1bv, fc2bv, molbv, nullptr, flag, N);
    // ---- GAT layer 3: x3 = agg@Wc3 + b3 (no relu); fused gate -> cat.h + d_out[:, :256]
    attn_dots_h_kernel<<<nodeBlocks, 256, 0, stream>>>(cat + 256, 512, was3, wad3, a_src, a_dst, 256, N);
    gat_agg_h_kernel<2><<<nodeBlocks, 256, 0, stream>>>(cat + 256, 512, 256, a_src, a_dst,
                                                        ptr_dst, idx_dst, agg, 512, N, E);
    gemm(agg, 512, Wc3, 512, cat, 512, 512, 256, Mp, 0, bv3, 0);
    gemm_gate_kernel<<<Mp / 128, 256, 0, stream>>>(cat, 512, Bcat, 512, 512,
                                                   fc1bv, fc2bv, molbv, d_out, flag, N);
    // ---- Hypergraph layer 1: xt = [h3|molx] @ theta1 (two passes), 2 gathers
    ingest_pad_molx_kernel<<<(N * 96 + 255) / 256, 256, 0, stream>>>(molx, mxp2, 96, N * 96, flag);
    gemm(cat + 256, 512, th1ta, 256, xt, 128, 256, 128, Mp, 0, nullptr, 0);
    gemm(mxp2, 96, th1tb, 96, xt, 128, 96, 128, Mp, 1, nullptr, 0);
    hyper_gather_kernel<<<nodeBlocks, 256, 0, stream>>>(xt, ptr_dst, idx_dst, (const u16*)nullptr,
                                                        efb, 128, nullptr, 0, flag, 0, N, E);
    hyper_gather_kernel<<<nodeBlocks, 256, 0, stream>>>(efb, ptr_src, idx_src, hb1v,
                                                        hx1, 128, nullptr, 0, flag, 1, N, E);
    // ---- Hypergraph layer 2 -> d_out[:, 256:384]
    gemm(hx1, 128, th2t, 128, xt, 128, 128, 128, Mp, 0, nullptr, 0);
    hyper_gather_kernel<<<nodeBlocks, 256, 0, stream>>>(xt, ptr_dst, idx_dst, (const u16*)nullptr,
                                                        efb, 128, nullptr, 0, flag, 0, N, E);
    hyper_gather_kernel<<<nodeBlocks, 256, 0, stream>>>(efb, ptr_src, idx_src, hb2v,
                                                        (u16*)nullptr, 0, d_out, 256, flag, 1, N, E);
}

// Round 8
// 2091.604 us; speedup vs baseline: 1.1004x; 1.1004x over previous
//
#include <hip/hip_runtime.h>

typedef unsigned short u16;
typedef __attribute__((ext_vector_type(8))) short short8v;    // MFMA A/B frag (8 bf16)
typedef __attribute__((ext_vector_type(8))) unsigned short ushort8v;
typedef __attribute__((ext_vector_type(4))) unsigned short ushort4v;
typedef __attribute__((ext_vector_type(4))) float f32x4;
typedef __attribute__((ext_vector_type(2))) float f32x2;

__device__ __forceinline__ float bf2f(u16 u) {
    union { unsigned int i; float f; } v; v.i = ((unsigned int)u) << 16; return v.f;
}
__device__ __forceinline__ u16 f2bf(float f) {
    union { float f; unsigned int i; } v; v.f = f;
    unsigned int i = v.i;
    return (u16)((i + 0x7FFFu + ((i >> 16) & 1u)) >> 16);
}
__device__ __forceinline__ float leaky02(float x) { return x > 0.f ? x : 0.2f * x; }
// flag=1: input buffers are packed bf16; flag=0: fp32
__device__ __forceinline__ float load_in(const void* p, long i, int isbf) {
    return isbf ? bf2f(((const u16*)p)[i]) : ((const float*)p)[i];
}
// packed 2xf32 ops (dual-issue FP32 pipe)
__device__ __forceinline__ f32x2 pk_fma(f32x2 a, f32x2 b, f32x2 c) {
    f32x2 d;
    asm("v_pk_fma_f32 %0, %1, %2, %3" : "=v"(d) : "v"(a), "v"(b), "v"(c));
    return d;
}
__device__ __forceinline__ f32x2 pk_add(f32x2 a, f32x2 b) {
    f32x2 d;
    asm("v_pk_add_f32 %0, %1, %2" : "=v"(d) : "v"(a), "v"(b));
    return d;
}
// dword of 2 bf16 -> f32x2 {lo, hi}
__device__ __forceinline__ f32x2 bfpair(unsigned int d) {
    union { unsigned int i; float f; } lo, hi;
    lo.i = d << 16;
    hi.i = d & 0xFFFF0000u;
    f32x2 r; r.x = lo.f; r.y = hi.f; return r;
}
__device__ __forceinline__ float bperm_f(int addr, float v) {
    return __int_as_float(__builtin_amdgcn_ds_bpermute(addr, __float_as_int(v)));
}
__device__ __forceinline__ int bperm_i(int addr, int v) {
    return __builtin_amdgcn_ds_bpermute(addr, v);
}
// async global->LDS DMA, 16B per lane (dest must be wave-uniform-base + lane*16)
#define GLD_LDS16(g, s) __builtin_amdgcn_global_load_lds( \
    (const __attribute__((address_space(1))) void*)(g),   \
    (__attribute__((address_space(3))) void*)(s), 16, 0, 0)

// ---------------------------------------------------------------- dtype detect
__global__ void detect_kernel(const unsigned* __restrict__ w, int* __restrict__ flag) {
    __shared__ int cnt;
    int t = threadIdx.x;
    if (t == 0) cnt = 0;
    __syncthreads();
    unsigned x = w[t * 16];
    unsigned lo = x & 0xFFFFu;
    int e = (int)((x >> 7) & 0xFFu);
    int good = (lo == 0u) || (e >= 100 && e <= 140);
    atomicAdd(&cnt, good);
    __syncthreads();
    if (t == 0) *flag = (cnt > 128) ? 1 : 0;
}

// ---------------------------------------------------------------- CSR build (bucketed)
#define CSR_NBK 1024

__global__ __launch_bounds__(256)
void bucket_count_kernel(const int* __restrict__ ei, int* __restrict__ bcs,
                         int* __restrict__ bcd, int E_, int n, int SH) {
    __shared__ int hs[CSR_NBK], hd[CSR_NBK];
    const int t = threadIdx.x;
    for (int i = t; i < CSR_NBK; i += 256) { hs[i] = 0; hd[i] = 0; }
    __syncthreads();
    const int e0 = blockIdx.x * 4096;
    #pragma unroll
    for (int k = 0; k < 16; ++k) {
        int e = e0 + k * 256 + t;
        if (e < E_) {
            int s = ei[e], d = ei[E_ + e];
            if ((unsigned)s >= (unsigned)n) s = 0;
            if ((unsigned)d >= (unsigned)n) d = 0;
            atomicAdd(&hs[s >> SH], 1);
            atomicAdd(&hd[d >> SH], 1);
        }
    }
    __syncthreads();
    for (int i = t; i < CSR_NBK; i += 256) {
        if (hs[i]) atomicAdd(&bcs[i], hs[i]);
        if (hd[i]) atomicAdd(&bcd[i], hd[i]);
    }
}

__global__ void scan_excl_kernel(const int* __restrict__ deg, int* __restrict__ ptr, int n) {
    __shared__ int s_woff[17];
    __shared__ int s_carry;
    const int t = threadIdx.x;          // 1024 threads
    const int lane = t & 63, wid = t >> 6;
    if (t == 0) s_carry = 0;
    __syncthreads();
    for (int base = 0; base < n; base += 1024) {
        int i = base + t;
        int v = (i < n) ? deg[i] : 0;
        int incl = v;
        #pragma unroll
        for (int d = 1; d < 64; d <<= 1) {
            int x = __shfl_up(incl, d, 64);
            if (lane >= d) incl += x;
        }
        if (lane == 63) s_woff[wid] = incl;
        __syncthreads();
        if (t == 0) {
            int run = 0;
            #pragma unroll
            for (int w = 0; w < 16; ++w) { int x = s_woff[w]; s_woff[w] = run; run += x; }
            s_woff[16] = run;
        }
        __syncthreads();
        int excl = s_carry + s_woff[wid] + incl - v;
        if (i < n) ptr[i] = excl;
        __syncthreads();
        if (t == 0) s_carry += s_woff[16];
        __syncthreads();
    }
    if (t == 0) ptr[n] = s_carry;
}

__global__ void copy2_kernel(const int* __restrict__ a, int* __restrict__ b,
                             const int* __restrict__ c, int* __restrict__ d2, int n) {
    int i = blockIdx.x * 256 + threadIdx.x;
    if (i < n) { b[i] = a[i]; d2[i] = c[i]; }
}

__global__ __launch_bounds__(256)
void partition_kernel(const int* __restrict__ ei, int* __restrict__ bcur_s,
                      int* __restrict__ bcur_d, int2* __restrict__ ps,
                      int2* __restrict__ pd, int E_, int n, int SH) {
    __shared__ int cs[CSR_NBK], cd[CSR_NBK], bs[CSR_NBK], bd[CSR_NBK];
    const int t = threadIdx.x;
    for (int i = t; i < CSR_NBK; i += 256) { cs[i] = 0; cd[i] = 0; }
    __syncthreads();
    const int e0 = blockIdx.x * 4096;
    int sv[16], dv[16];
    #pragma unroll
    for (int k = 0; k < 16; ++k) {
        int e = e0 + k * 256 + t;
        int s = -1, d = 0;
        if (e < E_) {
            s = ei[e]; d = ei[E_ + e];
            if ((unsigned)s >= (unsigned)n) s = 0;
            if ((unsigned)d >= (unsigned)n) d = 0;
            atomicAdd(&cs[s >> SH], 1);
            atomicAdd(&cd[d >> SH], 1);
        }
        sv[k] = (e < E_) ? s : -1;
        dv[k] = d;
    }
    __syncthreads();
    for (int i = t; i < CSR_NBK; i += 256) {
        bs[i] = cs[i] ? atomicAdd(&bcur_s[i], cs[i]) : 0;
        bd[i] = cd[i] ? atomicAdd(&bcur_d[i], cd[i]) : 0;
        cs[i] = 0; cd[i] = 0;
    }
    __syncthreads();
    #pragma unroll
    for (int k = 0; k < 16; ++k) {
        int s = sv[k];
        if (s < 0) continue;
        int d = dv[k];
        int p = bs[s >> SH] + atomicAdd(&cs[s >> SH], 1);
        ps[p] = make_int2(d, s);          // (payload, key)
        int q = bd[d >> SH] + atomicAdd(&cd[d >> SH], 1);
        pd[q] = make_int2(s, d);
    }
}

__global__ __launch_bounds__(256)
void fill_bucket_kernel(const int2* __restrict__ pairs, const int* __restrict__ bptr,
                        int* __restrict__ ptr, int* __restrict__ idx, int n, int SH) {
    __shared__ int cnt[256];
    __shared__ int wsum[5];
    const int b = blockIdx.x;
    const int n0 = b << SH;
    if (n0 >= n) return;
    const int nn = min(1 << SH, n - n0);
    const int t = threadIdx.x;
    cnt[t] = 0;
    __syncthreads();
    const int pbeg = bptr[b], pend = bptr[b + 1];
    for (int j = pbeg + t; j < pend; j += 256)
        atomicAdd(&cnt[pairs[j].y - n0], 1);
    __syncthreads();
    const int c = (t < nn) ? cnt[t] : 0;
    int v = c;
    const int lane = t & 63, wid = t >> 6;
    #pragma unroll
    for (int d = 1; d < 64; d <<= 1) {
        int x = __shfl_up(v, d, 64);
        if (lane >= d) v += x;
    }
    if (lane == 63) wsum[wid] = v;
    __syncthreads();
    if (t == 0) {
        int r = 0;
        #pragma unroll
        for (int w = 0; w < 4; ++w) { int x = wsum[w]; wsum[w] = r; r += x; }
        wsum[4] = r;
    }
    __syncthreads();
    v += wsum[wid];
    const int excl = pbeg + v - c;        // exclusive offset for node n0+t
    __syncthreads();                       // all reads of cnt done; safe to overwrite
    if (t < nn) { cnt[t] = excl; ptr[n0 + t] = excl; }
    if (t == 0 && n0 + nn == n) ptr[n] = pbeg + wsum[4];   // == pend
    __syncthreads();
    for (int j = pbeg + t; j < pend; j += 256) {
        int2 pr = pairs[j];
        int p = atomicAdd(&cnt[pr.y - n0], 1);
        idx[p] = pr.x;
    }
}

// ---------------------------------------------------------------- ingest (dtype-aware)
__global__ void ingest_transpose_kernel(const void* __restrict__ src, long base,
                                        u16* __restrict__ dst, int K, int Nc, int Kp,
                                        const int* __restrict__ flag) {
    int i = blockIdx.x * 256 + threadIdx.x;
    if (i >= Nc * Kp) return;
    int n = i / Kp, k = i - n * Kp;
    float v = (k < K) ? load_in(src, base + (long)k * Nc + n, *flag) : 0.f;
    dst[i] = f2bf(v);
}

// 8 small bias/vector copies batched into one launch (blocks 0-5: 256, 6-7: 128)
__global__ void ingest_vecs_kernel(const void* __restrict__ s0, const void* __restrict__ s1,
                                   const void* __restrict__ s2, const void* __restrict__ s3,
                                   const void* __restrict__ s4, const void* __restrict__ s5,
                                   const void* __restrict__ s6, const void* __restrict__ s7,
                                   u16* __restrict__ d0, u16* __restrict__ d1,
                                   u16* __restrict__ d2, u16* __restrict__ d3,
                                   u16* __restrict__ d4, u16* __restrict__ d5,
                                   u16* __restrict__ d6, u16* __restrict__ d7,
                                   const int* __restrict__ flag) {
    const void* srcs[8] = {s0, s1, s2, s3, s4, s5, s6, s7};
    u16* dsts[8] = {d0, d1, d2, d3, d4, d5, d6, d7};
    const int b = blockIdx.x, t = threadIdx.x;
    const int nsz = (b < 6) ? 256 : 128;
    if (t < nsz) dsts[b][t] = f2bf(load_in(srcs[b], t, *flag));
}

__global__ void ingest_wcat_kernel(const void* __restrict__ W, u16* __restrict__ dst,
                                   int Kin, int Fh, const int* __restrict__ flag) {
    int i = blockIdx.x * 256 + threadIdx.x;
    int tot = 256 * 2 * Fh;
    if (i >= tot) return;
    int o = i / (2 * Fh), k = i - o * 2 * Fh;
    int h = k / Fh, c = k - h * Fh;
    float v = (c < Kin) ? 0.5f * load_in(W, (long)c * 512 + h * 256 + o, *flag) : 0.f;
    dst[i] = f2bf(v);
}

__global__ void ingest_bcat_kernel(const void* __restrict__ fc1, const void* __restrict__ fc2,
                                   u16* __restrict__ dst, const int* __restrict__ flag) {
    int i = blockIdx.x * 256 + threadIdx.x;
    if (i >= 256 * 512) return;
    int o = i >> 9, k = i & 511;
    float v = (k < 256) ? load_in(fc1, (long)o * 256 + k, *flag)
                        : load_in(fc2, (long)o * 256 + k - 256, *flag);
    dst[i] = f2bf(v);
}

__global__ void ingest_pad_molx_kernel(const void* __restrict__ x, u16* __restrict__ dst,
                                       int ldd, int total, const int* __restrict__ flag) {
    int i = blockIdx.x * 256 + threadIdx.x;
    if (i >= total) return;
    int r = i / 96, c = i - r * 96;
    float v = (c < 78) ? load_in(x, (long)r * 78 + c, *flag) : 0.f;
    dst[(size_t)r * ldd + c] = f2bf(v);
}

__global__ void attn_vec_kernel(const void* __restrict__ W, const void* __restrict__ as_,
                                const void* __restrict__ ad_, float* __restrict__ was,
                                float* __restrict__ wad, int Kin, int Fh,
                                const int* __restrict__ flag) {
    int i = blockIdx.x * 256 + threadIdx.x;
    if (i >= 2 * Fh) return;
    int h = i / Fh, c = i - h * Fh;
    float s = 0.f, d = 0.f;
    if (c < Kin) {
        int f = *flag;
        for (int o = 0; o < 256; ++o) {
            float w = load_in(W, (long)c * 512 + h * 256 + o, f);
            s += w * load_in(as_, h * 256 + o, f);
            d += w * load_in(ad_, h * 256 + o, f);
        }
    }
    was[i] = s; wad[i] = d;
}

// ---------------------------------------------------------------- GEMM (bf16 MFMA)
// Staging via global_load_lds width-16 DMA. LDS dest = wave*1024 + lane*16 (legal DMA).
__global__ __launch_bounds__(256, 2)
void gemm_kernel(const u16* __restrict__ A, int lda,
                 const u16* __restrict__ Bt, int ldb,
                 u16* __restrict__ C, int ldc, int K, int M, int beta,
                 const u16* __restrict__ bias, int relu) {
    __shared__ __align__(16) u16 As[128 * 32];
    __shared__ __align__(16) u16 Bs[128 * 32];
    const int tid = threadIdx.x;
    const int wave = tid >> 6, lane = tid & 63;
    const int m0 = blockIdx.x * 128;
    const int n0 = blockIdx.y * 128;
    const int wm = (wave & 1) * 64, wn = (wave >> 1) * 64;
    const int r = lane & 15, q = lane >> 4;

    f32x4 acc[4][4];
    if (beta) {
        #pragma unroll
        for (int i = 0; i < 4; ++i)
            #pragma unroll
            for (int j = 0; j < 4; ++j)
                #pragma unroll
                for (int rr = 0; rr < 4; ++rr) {
                    size_t gr = (size_t)(m0 + wm + 16 * i + q * 4 + rr);
                    int gc = n0 + wn + 16 * j + r;
                    acc[i][j][rr] = bf2f(C[gr * ldc + gc]);
                }
    } else {
        #pragma unroll
        for (int i = 0; i < 4; ++i)
            #pragma unroll
            for (int j = 0; j < 4; ++j) acc[i][j] = (f32x4)0.f;
    }

    const int rowT = wave * 16 + (lane >> 2);
    const int koff = (lane & 3) * 8;
    int rA0 = m0 + rowT;       if (rA0 > M - 1) rA0 = M - 1;
    int rA1 = m0 + rowT + 64;  if (rA1 > M - 1) rA1 = M - 1;
    const u16* gA0 = A + (size_t)rA0 * lda + koff;
    const u16* gA1 = A + (size_t)rA1 * lda + koff;
    const u16* gB0 = Bt + (size_t)(n0 + rowT) * ldb + koff;
    const u16* gB1 = Bt + (size_t)(n0 + rowT + 64) * ldb + koff;
    u16* sA0 = &As[rowT * 32 + koff];
    u16* sA1 = &As[(rowT + 64) * 32 + koff];
    u16* sB0 = &Bs[rowT * 32 + koff];
    u16* sB1 = &Bs[(rowT + 64) * 32 + koff];

    const int nK = K >> 5;
    for (int kt = 0; kt < nK; ++kt) {
        __syncthreads();
        GLD_LDS16(gA0, sA0);
        GLD_LDS16(gA1, sA1);
        GLD_LDS16(gB0, sB0);
        GLD_LDS16(gB1, sB1);
        gA0 += 32; gA1 += 32; gB0 += 32; gB1 += 32;
        __syncthreads();
        short8v af[4], bf[4];
        #pragma unroll
        for (int i = 0; i < 4; ++i) af[i] = *(const short8v*)&As[(wm + 16 * i + r) * 32 + q * 8];
        #pragma unroll
        for (int j = 0; j < 4; ++j) bf[j] = *(const short8v*)&Bs[(wn + 16 * j + r) * 32 + q * 8];
        #pragma unroll
        for (int i = 0; i < 4; ++i)
            #pragma unroll
            for (int j = 0; j < 4; ++j)
                acc[i][j] = __builtin_amdgcn_mfma_f32_16x16x32_bf16(af[i], bf[j], acc[i][j], 0, 0, 0);
    }
    // C/D layout: col = lane&15, row = (lane>>4)*4 + reg
    #pragma unroll
    for (int j = 0; j < 4; ++j) {
        int gc = n0 + wn + 16 * j + r;
        float bv = bias ? bf2f(bias[gc]) : 0.f;
        #pragma unroll
        for (int i = 0; i < 4; ++i)
            #pragma unroll
            for (int rr = 0; rr < 4; ++rr) {
                size_t gr = (size_t)(m0 + wm + 16 * i + q * 4 + rr);
                float x = acc[i][j][rr] + bv;
                if (relu) x = fmaxf(x, 0.f);
                C[gr * ldc + gc] = f2bf(x);
            }
    }
}

// ---------------------------------------------------------------- attention dots (h-space)
__global__ __launch_bounds__(256)
void attn_dots_h_kernel(const u16* __restrict__ hsrc, int ldh,
                        const float* __restrict__ was, const float* __restrict__ wad,
                        float* __restrict__ a_src, float* __restrict__ a_dst,
                        int Fh, int n) {
    int v = blockIdx.x * 4 + (threadIdx.x >> 6);
    if (v >= n) return;
    const int lane = threadIdx.x & 63;
    const int c0 = lane * 4;
    float ps0 = 0.f, pd0 = 0.f, ps1 = 0.f, pd1 = 0.f;
    if (c0 < Fh) {
        ushort4v xv = *(const ushort4v*)&hsrc[(size_t)v * ldh + c0];
        #pragma unroll
        for (int k = 0; k < 4; ++k) {
            float x = bf2f(xv[k]);
            ps0 += x * was[c0 + k];
            pd0 += x * wad[c0 + k];
            ps1 += x * was[Fh + c0 + k];
            pd1 += x * wad[Fh + c0 + k];
        }
    }
    #pragma unroll
    for (int d = 1; d < 64; d <<= 1) {
        ps0 += __shfl_xor(ps0, d, 64); pd0 += __shfl_xor(pd0, d, 64);
        ps1 += __shfl_xor(ps1, d, 64); pd1 += __shfl_xor(pd1, d, 64);
    }
    if (lane == 0) {
        a_src[2 * v] = ps0; a_src[2 * v + 1] = ps1;
        a_dst[2 * v] = pd0; a_dst[2 * v + 1] = pd1;
    }
}

// ---------------------------------------------------------------- GAT aggregate
// Round-3 bperm structure + no-max softmax (scores O(+-2); clamp 80 for inf-safety;
// exp shift-invariance makes the max pass optional). Weight phase: one edge per lane,
// exp computed ONCE per edge. Feature phase: wave-uniform trip count; (src,w) via
// register bperm. Lanes >= cnt stay ACTIVE with w=0 -> bperm sources always valid.
template <int NG>
__global__ __launch_bounds__(256)
void gat_agg_h_kernel(const u16* __restrict__ hsrc, int ldh, int F,
                      const float* __restrict__ asrc, const float* __restrict__ adst,
                      const int* __restrict__ ptr, const int* __restrict__ idx,
                      u16* __restrict__ agg, int ldagg, int n, int Etot) {
    constexpr int GL = 64 / NG;           // lanes per edge group
    int v = blockIdx.x * 4 + (threadIdx.x >> 6);
    if (v >= n) return;
    const int lane = threadIdx.x & 63;
    const int sub = lane / GL;            // edge slot within chunk parity
    const int c0 = (lane & (GL - 1)) * 8; // 8 cols per lane
    const int act = (c0 < F);
    int beg = ptr[v], end = ptr[v + 1];
    beg = min(max(beg, 0), Etot);
    end = min(max(end, beg), Etot);
    const float ad0 = adst[2 * v], ad1 = adst[2 * v + 1];
    const float es0 = fminf(leaky02(asrc[2 * v] + ad0), 80.f);
    const float es1 = fminf(leaky02(asrc[2 * v + 1] + ad1), 80.f);
    float s0 = 0.f, s1 = 0.f;             // per-lane partial exp-sums
    f32x2 f0p[4], f1p[4];
    #pragma unroll
    for (int p = 0; p < 4; ++p) { f0p[p] = (f32x2)0.f; f1p[p] = (f32x2)0.f; }

    for (int cb = beg; cb < end; cb += 64) {
        const int cnt = min(64, end - cb);   // wave-uniform
        // ---- weight phase: one edge per lane; lanes >= cnt hold weight 0
        int sE = 0;
        float wE0 = 0.f, wE1 = 0.f;
        if (lane < cnt) {
            sE = idx[cb + lane];
            sE = ((unsigned)sE < (unsigned)n) ? sE : 0;
            const float2 ap = *(const float2*)&asrc[2 * sE];
            wE0 = __expf(fminf(leaky02(ap.x + ad0), 80.f));
            wE1 = __expf(fminf(leaky02(ap.y + ad1), 80.f));
            s0 += wE0; s1 += wE1;
        }
        // ---- feature phase: NG edges in flight, wave-uniform trip count.
        // max source lane = nIt*2NG - 1 <= 63 (cnt <= 64, 2NG | 64): no clamp needed.
        const int nIt = (cnt + 2 * NG - 1) / (2 * NG);
        int jj = sub;
        for (int it = 0; it < nIt; ++it, jj += 2 * NG) {
            const int aA = jj * 4, aB = aA + NG * 4;
            const int sA = bperm_i(aA, sE);
            const float wA0 = bperm_f(aA, wE0), wA1 = bperm_f(aA, wE1);
            const int sB = bperm_i(aB, sE);
            const float wB0 = bperm_f(aB, wE0), wB1 = bperm_f(aB, wE1);
            if (act) {
                const uint4 fA = *(const uint4*)&hsrc[(size_t)sA * ldh + c0];
                const uint4 fB = *(const uint4*)&hsrc[(size_t)sB * ldh + c0];
                const f32x2 wA0v = {wA0, wA0}, wA1v = {wA1, wA1};
                const f32x2 wB0v = {wB0, wB0}, wB1v = {wB1, wB1};
                #pragma unroll
                for (int p = 0; p < 4; ++p) {
                    const f32x2 xA = bfpair(((const unsigned*)&fA)[p]);
                    const f32x2 xB = bfpair(((const unsigned*)&fB)[p]);
                    f0p[p] = pk_fma(xA, wA0v, f0p[p]);
                    f1p[p] = pk_fma(xA, wA1v, f1p[p]);
                    f0p[p] = pk_fma(xB, wB0v, f0p[p]);
                    f1p[p] = pk_fma(xB, wB1v, f1p[p]);
                }
            }
        }
    }
    // reduce exp-sums across all 64 lanes
    #pragma unroll
    for (int d = 1; d < 64; d <<= 1) {
        s0 += __shfl_xor(s0, d, 64);
        s1 += __shfl_xor(s1, d, 64);
    }
    const float w0s = __expf(es0), w1s = __expf(es1);
    s0 += w0s; s1 += w1s;
    if (sub == 0 && act) {   // self-loop features
        const uint4 f = *(const uint4*)&hsrc[(size_t)v * ldh + c0];
        const f32x2 w0v = {w0s, w0s}, w1v = {w1s, w1s};
        #pragma unroll
        for (int p = 0; p < 4; ++p) {
            const f32x2 x = bfpair(((const unsigned*)&f)[p]);
            f0p[p] = pk_fma(x, w0v, f0p[p]);
            f1p[p] = pk_fma(x, w1v, f1p[p]);
        }
    }
    // reduce feature partials across edge groups
    #pragma unroll
    for (int p = 0; p < 4; ++p) {
        #pragma unroll
        for (int d = GL; d < 64; d <<= 1) {
            f0p[p].x += __shfl_xor(f0p[p].x, d, 64);
            f0p[p].y += __shfl_xor(f0p[p].y, d, 64);
            f1p[p].x += __shfl_xor(f1p[p].x, d, 64);
            f1p[p].y += __shfl_xor(f1p[p].y, d, 64);
        }
    }
    if (lane < GL && act) {
        const float i0 = 1.f / s0, i1 = 1.f / s1;
        ushort8v o0, o1;
        #pragma unroll
        for (int p = 0; p < 4; ++p) {
            o0[2 * p] = f2bf(f0p[p].x * i0); o0[2 * p + 1] = f2bf(f0p[p].y * i0);
            o1[2 * p] = f2bf(f1p[p].x * i1); o1[2 * p + 1] = f2bf(f1p[p].y * i1);
        }
        *(ushort8v*)&agg[(size_t)v * ldagg + c0] = o0;
        *(ushort8v*)&agg[(size_t)v * ldagg + F + c0] = o1;
    }
}

// ---------------------------------------------------------------- gate (GRU-style)
__global__ __launch_bounds__(256)
void gate_kernel(const u16* __restrict__ logit, const u16* __restrict__ cat,
                 const u16* __restrict__ fc1b, const u16* __restrict__ fc2b,
                 const u16* __restrict__ molb, u16* __restrict__ dest,
                 void* __restrict__ outw, const int* __restrict__ flag, int n) {
    int i = blockIdx.x * 256 + threadIdx.x;
    if (i >= n) return;
    int node = i >> 5, c0 = (i & 31) * 8;
    ushort8v lg = *(const ushort8v*)&logit[(size_t)node * 256 + c0];
    ushort8v xv = *(const ushort8v*)&cat[(size_t)node * 512 + c0];
    ushort8v hv = *(const ushort8v*)&cat[(size_t)node * 512 + 256 + c0];
    ushort8v b1v = *(const ushort8v*)&fc1b[c0];
    ushort8v b2v = *(const ushort8v*)&fc2b[c0];
    ushort8v mbv = *(const ushort8v*)&molb[c0];
    float ov[8];
    ushort8v dv;
    #pragma unroll
    for (int k = 0; k < 8; ++k) {
        float l = bf2f(lg[k]) + bf2f(b1v[k]) + bf2f(b2v[k]) + bf2f(mbv[k]);
        float z = 1.f / (1.f + __expf(-l));
        ov[k] = z * bf2f(xv[k]) + (1.f - z) * bf2f(hv[k]);
        dv[k] = f2bf(ov[k]);
    }
    *(ushort8v*)&dest[(size_t)node * 512 + c0] = dv;
    if (outw) {
        if (*flag) {
            *(ushort8v*)((u16*)outw + (size_t)node * 384 + c0) = dv;
        } else {
            float* o = (float*)outw + (size_t)node * 384 + c0;
            #pragma unroll
            for (int k = 0; k < 8; ++k) o[k] = ov[k];
        }
    }
}

// ---------------------------------------------------------------- hypergraph gather
// res[v] = inv_deg * sum feat[idx[j]] (+bias, relu); F=128 fixed. 4 sub-groups x
// 4 rows in flight (16 concurrent gathers/wave), pk add.
__global__ __launch_bounds__(256)
void hyper_gather_kernel(const u16* __restrict__ feat, const int* __restrict__ ptr,
                         const int* __restrict__ idx, const u16* __restrict__ bias,
                         u16* __restrict__ outb, int ldo, void* __restrict__ outw,
                         int col0, const int* __restrict__ flag,
                         int do_relu, int n, int Etot) {
    int v = blockIdx.x * 4 + (threadIdx.x >> 6);
    if (v >= n) return;
    const int lane = threadIdx.x & 63;
    const int c0 = (lane & 15) * 8, sub = lane >> 4;
    int beg = ptr[v], end = ptr[v + 1];
    beg = min(max(beg, 0), Etot);
    end = min(max(end, beg), Etot);
    const float inv = (end > beg) ? 1.f / (float)(end - beg) : 0.f;
    f32x2 a2[4];
    #pragma unroll
    for (int p = 0; p < 4; ++p) a2[p] = (f32x2)0.f;
    int j = beg + sub;
    for (; j + 12 < end; j += 16) {
        int sA = idx[j];      sA = ((unsigned)sA < (unsigned)n) ? sA : 0;
        int sB = idx[j + 4];  sB = ((unsigned)sB < (unsigned)n) ? sB : 0;
        int sC = idx[j + 8];  sC = ((unsigned)sC < (unsigned)n) ? sC : 0;
        int sD = idx[j + 12]; sD = ((unsigned)sD < (unsigned)n) ? sD : 0;
        const uint4 fA = *(const uint4*)&feat[(size_t)sA * 128 + c0];
        const uint4 fB = *(const uint4*)&feat[(size_t)sB * 128 + c0];
        const uint4 fC = *(const uint4*)&feat[(size_t)sC * 128 + c0];
        const uint4 fD = *(const uint4*)&feat[(size_t)sD * 128 + c0];
        #pragma unroll
        for (int p = 0; p < 4; ++p) {
            a2[p] = pk_add(a2[p], bfpair(((const unsigned*)&fA)[p]));
            a2[p] = pk_add(a2[p], bfpair(((const unsigned*)&fB)[p]));
            a2[p] = pk_add(a2[p], bfpair(((const unsigned*)&fC)[p]));
            a2[p] = pk_add(a2[p], bfpair(((const unsigned*)&fD)[p]));
        }
    }
    for (; j < end; j += 4) {
        int s = idx[j]; s = ((unsigned)s < (unsigned)n) ? s : 0;
        const uint4 f = *(const uint4*)&feat[(size_t)s * 128 + c0];
        #pragma unroll
        for (int p = 0; p < 4; ++p)
            a2[p] = pk_add(a2[p], bfpair(((const unsigned*)&f)[p]));
    }
    #pragma unroll
    for (int p = 0; p < 4; ++p) {
        a2[p].x += __shfl_xor(a2[p].x, 16, 64);
        a2[p].y += __shfl_xor(a2[p].y, 16, 64);
        a2[p].x += __shfl_xor(a2[p].x, 32, 64);
        a2[p].y += __shfl_xor(a2[p].y, 32, 64);
    }
    if (sub == 0) {
        float ov[8];
        ushort8v o;
        #pragma unroll
        for (int p = 0; p < 4; ++p) {
            float x0 = a2[p].x * inv + (bias ? bf2f(bias[c0 + 2 * p]) : 0.f);
            float x1 = a2[p].y * inv + (bias ? bf2f(bias[c0 + 2 * p + 1]) : 0.f);
            if (do_relu) { x0 = fmaxf(x0, 0.f); x1 = fmaxf(x1, 0.f); }
            ov[2 * p] = x0; ov[2 * p + 1] = x1;
            o[2 * p] = f2bf(x0); o[2 * p + 1] = f2bf(x1);
        }
        if (outb) *(ushort8v*)&outb[(size_t)v * ldo + c0] = o;
        if (outw) {
            if (*flag) {
                *(ushort8v*)((u16*)outw + (size_t)v * 384 + col0 + c0) = o;
            } else {
                float* ofp = (float*)outw + (size_t)v * 384 + col0 + c0;
                #pragma unroll
                for (int k = 0; k < 8; ++k) ofp[k] = ov[k];
            }
        }
    }
}

// ================================================================ launch
extern "C" void kernel_launch(void* const* d_in, const int* in_sizes, int n_in,
                              void* d_out, int out_size, void* d_ws, size_t ws_size,
                              hipStream_t stream) {
    const void* molx = d_in[0];
    const int*  ei   = (const int*)d_in[1];
    const void* W1 = d_in[3], *as1 = d_in[4], *ad1 = d_in[5], *b1 = d_in[6];
    const void* W2 = d_in[7], *as2 = d_in[8], *ad2 = d_in[9], *b2 = d_in[10];
    const void* W3 = d_in[11], *as3 = d_in[12], *ad3 = d_in[13], *b3 = d_in[14];
    const void* fc1w = d_in[15], *fc1b = d_in[16], *fc2w = d_in[17], *fc2b = d_in[18];
    const void* molb = d_in[19];
    const void* th1 = d_in[20], *hb1 = d_in[21], *th2 = d_in[22], *hb2 = d_in[23];
    (void)n_in; (void)out_size;

    const int N = in_sizes[0] / 78;
    const int E = in_sizes[1] / 2;
    const int Mp = ((N + 127) / 128) * 128;

    // bucket shift: at most 1024 buckets, bucket width <= 256 nodes (N <= 262144)
    int SH = 0;
    while (((N - 1) >> SH) >= CSR_NBK) SH++;

    // ---- workspace
    char* base = (char*)d_ws;
    size_t off = 0;
    auto alloc = [&](size_t bytes) -> void* {
        void* r = base + off;
        off = (off + bytes + 255) & ~(size_t)255;
        return r;
    };
    int* flag = (int*)alloc(4);
    u16* bv1 = (u16*)alloc(256 * 2); u16* bv2 = (u16*)alloc(256 * 2); u16* bv3 = (u16*)alloc(256 * 2);
    u16* fc1bv = (u16*)alloc(256 * 2); u16* fc2bv = (u16*)alloc(256 * 2); u16* molbv = (u16*)alloc(256 * 2);
    u16* hb1v = (u16*)alloc(128 * 2); u16* hb2v = (u16*)alloc(128 * 2);
    float* was1 = (float*)alloc(192 * 4); float* wad1 = (float*)alloc(192 * 4);
    float* was2 = (float*)alloc(512 * 4); float* wad2 = (float*)alloc(512 * 4);
    float* was3 = (float*)alloc(512 * 4); float* wad3 = (float*)alloc(512 * 4);
    u16* Wc1 = (u16*)alloc(256 * 192 * 2);
    u16* Wc2 = (u16*)alloc(256 * 512 * 2);
    u16* Wc3 = (u16*)alloc(256 * 512 * 2);
    u16* Bcat = (u16*)alloc(256 * 512 * 2);
    u16* th1ta = (u16*)alloc(128 * 256 * 2);
    u16* th1tb = (u16*)alloc(128 * 96 * 2);
    u16* th2t  = (u16*)alloc(128 * 128 * 2);
    float* a_src = (float*)alloc((size_t)N * 2 * 4);
    float* a_dst = (float*)alloc((size_t)N * 2 * 4);
    int* ptr_src = (int*)alloc((size_t)(N + 1) * 4);
    int* ptr_dst = (int*)alloc((size_t)(N + 1) * 4);
    int* bcnt_src = (int*)alloc(CSR_NBK * 4);
    int* bcnt_dst = (int*)alloc(CSR_NBK * 4);
    int* bptr_src = (int*)alloc((CSR_NBK + 1) * 4);
    int* bptr_dst = (int*)alloc((CSR_NBK + 1) * 4);
    int* bcur_src = (int*)alloc(CSR_NBK * 4);
    int* bcur_dst = (int*)alloc(CSR_NBK * 4);
    int* idx_src = (int*)alloc((size_t)E * 4);
    int* idx_dst = (int*)alloc((size_t)E * 4);
    u16* cat = (u16*)alloc((size_t)Mp * 512 * 2);   // [x | h] per row (ld 512)
    u16* agg = (u16*)alloc((size_t)Mp * 512 * 2);   // agg / logits / hyper regions
    // hyper-phase regions inside agg:
    u16* xt   = agg;                         // Mp x 128
    u16* efb  = agg + (size_t)Mp * 128;      // N x 128
    u16* hx1  = agg + (size_t)Mp * 256;      // N x 128
    u16* mxp2 = agg + (size_t)Mp * 384;      // Mp x 96 (re-ingested mol_x for hyper GEMM)

    // pair buffers (bucket-major (payload,key)): dedicated if ws allows, else borrow agg
    int2* pairs_src; int2* pairs_dst;
    if (off + (size_t)E * 16 + 1024 <= ws_size) {
        pairs_src = (int2*)alloc((size_t)E * 8);
        pairs_dst = (int2*)alloc((size_t)E * 8);
    } else {
        pairs_src = (int2*)agg;
        pairs_dst = (int2*)((char*)agg + (size_t)E * 8);
    }

    const int nodeBlocks = (N + 3) / 4;
    const int eTiles = (E + 4095) / 4096;

    // ---- dtype detect (precedes all ingest)
    detect_kernel<<<1, 256, 0, stream>>>((const unsigned*)molx, flag);

    // ---- CSR build (bucketed two-level scatter)
    hipMemsetAsync(bcnt_src, 0, CSR_NBK * 4, stream);
    hipMemsetAsync(bcnt_dst, 0, CSR_NBK * 4, stream);
    bucket_count_kernel<<<eTiles, 256, 0, stream>>>(ei, bcnt_src, bcnt_dst, E, N, SH);
    scan_excl_kernel<<<1, 1024, 0, stream>>>(bcnt_src, bptr_src, CSR_NBK);
    scan_excl_kernel<<<1, 1024, 0, stream>>>(bcnt_dst, bptr_dst, CSR_NBK);
    copy2_kernel<<<(CSR_NBK + 255) / 256, 256, 0, stream>>>(bptr_src, bcur_src, bptr_dst, bcur_dst, CSR_NBK);
    partition_kernel<<<eTiles, 256, 0, stream>>>(ei, bcur_src, bcur_dst,
                                                 pairs_src, pairs_dst, E, N, SH);
    fill_bucket_kernel<<<CSR_NBK, 256, 0, stream>>>(pairs_src, bptr_src, ptr_src, idx_src, N, SH);
    fill_bucket_kernel<<<CSR_NBK, 256, 0, stream>>>(pairs_dst, bptr_dst, ptr_dst, idx_dst, N, SH);

    // ---- weight/vector ingest
    ingest_wcat_kernel<<<(256 * 192 + 255) / 256, 256, 0, stream>>>(W1, Wc1, 78, 96, flag);
    ingest_wcat_kernel<<<(256 * 512 + 255) / 256, 256, 0, stream>>>(W2, Wc2, 256, 256, flag);
    ingest_wcat_kernel<<<(256 * 512 + 255) / 256, 256, 0, stream>>>(W3, Wc3, 256, 256, flag);
    ingest_bcat_kernel<<<(256 * 512 + 255) / 256, 256, 0, stream>>>(fc1w, fc2w, Bcat, flag);
    ingest_transpose_kernel<<<(128 * 256 + 255) / 256, 256, 0, stream>>>(th1, 0, th1ta, 256, 128, 256, flag);
    ingest_transpose_kernel<<<(128 * 96 + 255) / 256, 256, 0, stream>>>(th1, (long)256 * 128, th1tb, 78, 128, 96, flag);
    ingest_transpose_kernel<<<(128 * 128 + 255) / 256, 256, 0, stream>>>(th2, 0, th2t, 128, 128, 128, flag);
    attn_vec_kernel<<<1, 256, 0, stream>>>(W1, as1, ad1, was1, wad1, 78, 96, flag);
    attn_vec_kernel<<<2, 256, 0, stream>>>(W2, as2, ad2, was2, wad2, 256, 256, flag);
    attn_vec_kernel<<<2, 256, 0, stream>>>(W3, as3, ad3, was3, wad3, 256, 256, flag);
    ingest_vecs_kernel<<<8, 256, 0, stream>>>(b1, b2, b3, fc1b, fc2b, molb, hb1, hb2,
                                              bv1, bv2, bv3, fc1bv, fc2bv, molbv,
                                              hb1v, hb2v, flag);
    // mol_x padded into cat cols [0,96) (x-region unused until layer 2)
    ingest_pad_molx_kernel<<<(N * 96 + 255) / 256, 256, 0, stream>>>(molx, cat, 512, N * 96, flag);

    auto gemm = [&](const u16* A, int lda, const u16* Bt, int ldb, u16* C, int ldc,
                    int K, int Nc, int M, int beta, const u16* bias, int relu) {
        dim3 g(Mp / 128, Nc / 128);
        gemm_kernel<<<g, 256, 0, stream>>>(A, lda, Bt, ldb, C, ldc, K, M, beta, bias, relu);
    };

    // ---- GAT layer 1: agg over mol_x (F=96) -> h1 = relu(agg@Wc1 + b1) -> cat.h
    attn_dots_h_kernel<<<nodeBlocks, 256, 0, stream>>>(cat, 512, was1, wad1, a_src, a_dst, 96, N);
    gat_agg_h_kernel<4><<<nodeBlocks, 256, 0, stream>>>(cat, 512, 96, a_src, a_dst,
                                                        ptr_dst, idx_dst, agg, 192, N, E);
    gemm(agg, 192, Wc1, 192, cat + 256, 512, 192, 256, Mp, 0, bv1, 1);
    // ---- GAT layer 2: agg over h1 -> x2 = relu(agg@Wc2 + b2) -> cat.x; gate -> cat.h
    attn_dots_h_kernel<<<nodeBlocks, 256, 0, stream>>>(cat + 256, 512, was2, wad2, a_src, a_dst, 256, N);
    gat_agg_h_kernel<2><<<nodeBlocks, 256, 0, stream>>>(cat + 256, 512, 256, a_src, a_dst,
                                                        ptr_dst, idx_dst, agg, 512, N, E);
    gemm(agg, 512, Wc2, 512, cat, 512, 512, 256, Mp, 0, bv2, 1);
    gemm(cat, 512, Bcat, 512, agg /*logits*/, 256, 512, 256, Mp, 0, nullptr, 0);
    gate_kernel<<<(N * 32 + 255) / 256, 256, 0, stream>>>(agg, cat, fc1bv, fc2bv, molbv,
                                                          cat + 256, nullptr, flag, N * 32);
    // ---- GAT layer 3: x3 = agg@Wc3 + b3 (no relu); gate -> cat.h + d_out[:, :256]
    attn_dots_h_kernel<<<nodeBlocks, 256, 0, stream>>>(cat + 256, 512, was3, wad3, a_src, a_dst, 256, N);
    gat_agg_h_kernel<2><<<nodeBlocks, 256, 0, stream>>>(cat + 256, 512, 256, a_src, a_dst,
                                                        ptr_dst, idx_dst, agg, 512, N, E);
    gemm(agg, 512, Wc3, 512, cat, 512, 512, 256, Mp, 0, bv3, 0);
    gemm(cat, 512, Bcat, 512, agg /*logits*/, 256, 512, 256, Mp, 0, nullptr, 0);
    gate_kernel<<<(N * 32 + 255) / 256, 256, 0, stream>>>(agg, cat, fc1bv, fc2bv, molbv,
                                                          cat + 256, d_out, flag, N * 32);
    // ---- Hypergraph layer 1: xt = [h3|molx] @ theta1 (two passes), 2 gathers
    ingest_pad_molx_kernel<<<(N * 96 + 255) / 256, 256, 0, stream>>>(molx, mxp2, 96, N * 96, flag);
    gemm(cat + 256, 512, th1ta, 256, xt, 128, 256, 128, Mp, 0, nullptr, 0);
    gemm(mxp2, 96, th1tb, 96, xt, 128, 96, 128, Mp, 1, nullptr, 0);
    hyper_gather_kernel<<<nodeBlocks, 256, 0, stream>>>(xt, ptr_dst, idx_dst, (const u16*)nullptr,
                                                        efb, 128, nullptr, 0, flag, 0, N, E);
    hyper_gather_kernel<<<nodeBlocks, 256, 0, stream>>>(efb, ptr_src, idx_src, hb1v,
                                                        hx1, 128, nullptr, 0, flag, 1, N, E);
    // ---- Hypergraph layer 2 -> d_out[:, 256:384]
    gemm(hx1, 128, th2t, 128, xt, 128, 128, 128, Mp, 0, nullptr, 0);
    hyper_gather_kernel<<<nodeBlocks, 256, 0, stream>>>(xt, ptr_dst, idx_dst, (const u16*)nullptr,
                                                        efb, 128, nullptr, 0, flag, 0, N, E);
    hyper_gather_kernel<<<nodeBlocks, 256, 0, stream>>>(efb, ptr_src, idx_src, hb2v,
                                                        (u16*)nullptr, 0, d_out, 256, flag, 1, N, E);
}